// Round 1
// baseline (93.443 us; speedup 1.0000x reference)
//
#include <hip/hip_runtime.h>

#define CROP 14
#define NPOS (CROP * CROP)      // 196
#define CHANNELS 256
#define CPB 64                   // channels per block
#define NCHUNK (CHANNELS / CPB)  // 4

__global__ __launch_bounds__(256) void crop_roi_kernel(
    const float* __restrict__ p2, const float* __restrict__ p3,
    const float* __restrict__ p4, const float* __restrict__ p5,
    const float* __restrict__ props, float* __restrict__ out)
{
    const int blk = blockIdx.x;
    const int n   = blk >> 2;            // proposal index (NCHUNK == 4)
    const int c0  = (blk & 3) * CPB;     // channel chunk base
    const int tid = threadIdx.x;

    __shared__ int   s_row0[CROP], s_row1[CROP];  // yi0*W, yi1*W
    __shared__ int   s_xi0[CROP],  s_xi1[CROP];
    __shared__ float s_ly[CROP],   s_lx[CROP];
    __shared__ const float* s_base;               // feat + b*C*H*W
    __shared__ int   s_HW;

    if (tid < 2 * CROP) {
        // per-proposal setup, redundantly computed by 28 threads (wave-uniform)
        const float bi = props[n * 7 + 0];
        const float x0 = props[n * 7 + 1];
        const float y0 = props[n * 7 + 2];
        const float x1 = props[n * 7 + 3];
        const float y1 = props[n * 7 + 4];

        const float w  = x1 - x0;
        const float h  = y1 - y0;
        const float sz = sqrtf(w * h);

        // argmin |sz - base|, first-occurrence tie-break (matches jnp.argmin)
        int lvl = 0;
        float bd = fabsf(sz - 8.0f);
        {
            float d;
            d = fabsf(sz - 16.0f); if (d < bd) { bd = d; lvl = 1; }
            d = fabsf(sz - 32.0f); if (d < bd) { bd = d; lvl = 2; }
            d = fabsf(sz - 64.0f); if (d < bd) { bd = d; lvl = 3; }
        }

        const int   H     = 256 >> lvl;                    // H == W per level
        const float scale = 0.25f / (float)(1 << lvl);     // 1/stride (exact)
        const int   b     = (int)bi;

        if (tid == 0) {
            const float* fp;
            switch (lvl) {
                case 0:  fp = p2; break;
                case 1:  fp = p3; break;
                case 2:  fp = p4; break;
                default: fp = p5; break;
            }
            s_base = fp + (size_t)b * CHANNELS * H * H;
            s_HW   = H * H;
        }

        if (tid < CROP) {
            const int iy = tid;
            const float g   = (float)iy / 13.0f;          // matches arange(14)/13
            const float ys0 = y0 * scale;
            const float ys1 = y1 * scale;
            const float ys  = ys0 + (ys1 - ys0) * g;      // ref op order
            const float yf  = floorf(ys);
            int yi0 = (int)yf;
            yi0 = min(max(yi0, 0), H - 1);
            const int yi1 = min(yi0 + 1, H - 1);
            s_row0[iy] = yi0 * H;
            s_row1[iy] = yi1 * H;
            s_ly[iy]   = ys - yf;                          // unclamped frac (ref)
        } else {
            const int ix = tid - CROP;
            const float g   = (float)ix / 13.0f;
            const float xs0 = x0 * scale;
            const float xs1 = x1 * scale;
            const float xs  = xs0 + (xs1 - xs0) * g;
            const float xf  = floorf(xs);
            int xi0 = (int)xf;
            xi0 = min(max(xi0, 0), H - 1);
            const int xi1 = min(xi0 + 1, H - 1);
            s_xi0[ix] = xi0;
            s_xi1[ix] = xi1;
            s_lx[ix]  = xs - xf;
        }
    }
    __syncthreads();

    const float* __restrict__ base = s_base;
    const int HW = s_HW;
    float* __restrict__ outp = out + ((size_t)n * CHANNELS + c0) * NPOS;

    // 64 channels * 196 positions = 12544 outputs, 49 iters of 256 threads.
    // idx walks the output chunk contiguously -> fully coalesced stores.
    for (int idx = tid; idx < CPB * NPOS; idx += 256) {
        const int c   = idx / NPOS;           // const-div -> magic mul
        const int pos = idx - c * NPOS;
        const int y   = pos / CROP;
        const int x   = pos - y * CROP;

        const float* __restrict__ fb = base + (size_t)(c0 + c) * HW;
        const int   r0  = s_row0[y];
        const int   r1  = s_row1[y];
        const int   xi0 = s_xi0[x];
        const int   xi1 = s_xi1[x];
        const float ly  = s_ly[y];
        const float lx  = s_lx[x];

        const float v00 = fb[r0 + xi0];
        const float v01 = fb[r0 + xi1];
        const float v10 = fb[r1 + xi0];
        const float v11 = fb[r1 + xi1];

        const float omy = 1.0f - ly;
        const float omx = 1.0f - lx;
        outp[idx] = v00 * omy * omx + v01 * omy * lx
                  + v10 * ly  * omx + v11 * ly  * lx;
    }
}

extern "C" void kernel_launch(void* const* d_in, const int* in_sizes, int n_in,
                              void* d_out, int out_size, void* d_ws, size_t ws_size,
                              hipStream_t stream) {
    const float* p2    = (const float*)d_in[0];
    const float* p3    = (const float*)d_in[1];
    const float* p4    = (const float*)d_in[2];
    const float* p5    = (const float*)d_in[3];
    const float* props = (const float*)d_in[4];
    float* outp        = (float*)d_out;

    const int N = in_sizes[4] / 7;           // 1024 proposals
    dim3 grid(N * NCHUNK);
    dim3 block(256);
    hipLaunchKernelGGL(crop_roi_kernel, grid, block, 0, stream,
                       p2, p3, p4, p5, props, outp);
}